// Round 17
// baseline (159.899 us; speedup 1.0000x reference)
//
#include <hip/hip_runtime.h>
#include <stdint.h>

#define NN 16384
#define MM 16384
#define DD 8
#define DV 16
#define WAVES 4
#define MT 2                        // 16-row m-tiles per wave
#define ROWS_WAVE (MT * 16)         // 32
#define ROWS_BLK (WAVES * ROWS_WAVE)// 128
#define JSPLIT 32
#define JCHUNK (MM / JSPLIT)        // 512
#define J32 (JCHUNK / 32)           // 16 iterations per block

typedef short bf8 __attribute__((ext_vector_type(8)));   // 8 bf16 (4 VGPR)
typedef short s2v __attribute__((ext_vector_type(2)));   // 2 bf16, one b32 store
typedef float f32x4 __attribute__((ext_vector_type(4))); // MFMA C/D

#define C3SQ 10.406844905028037f     /* 5*log2(e)^2 : folded into tables */
#define C2S  (1.2909944487358056f / 10.406844905028037f)  /* c2/c3sq */
#define LN2  0.6931471805599453f

__device__ __forceinline__ unsigned short f2bf(float f) {
    union { float f; uint32_t u; } c; c.f = f;
    uint32_t u = c.u + 0x7FFF + ((c.u >> 16) & 1);       // RNE
    return (unsigned short)(u >> 16);
}
__device__ __forceinline__ float bf2f(unsigned short h) {
    union { float f; uint32_t u; } c; c.u = ((uint32_t)h) << 16;
    return c.f;
}

// Full-rate-VALU exp2 for u <= 0: 2^u = ldexp(poly3(f), n), n=floor(u),
// f=u-n in [0,1). Cubic minimax rel-err ~2e-4 — invisible under bf16's
// 2e-3 rounding of k. Replaces the 16-cyc v_exp_f32 (trans pipe was 61%
// of the wall) with 7 full-rate VALU ops on the other pipe.
__device__ __forceinline__ float fast_exp2(float u) {
    float nf = __builtin_floorf(u);
    float f = u - nf;
    float p = fmaf(f, fmaf(f, fmaf(f, 0.078024523f, 0.22606716f), 0.69583354f), 1.f);
#if __has_builtin(__builtin_amdgcn_ldexpf)
    return __builtin_amdgcn_ldexpf(p, (int)nf);
#else
    return ldexpf(p, (int)nf);
#endif
}

#define BF16_ONE ((short)0x3F80)

// Prep (R15 shape): one WAVE per table tile -> 1536 waves.
//   waves    0..1023: ytbl[tile16]  (scaled d2 fold)
//   waves 1024..1535: btbl[tile32]  (PERMUTED K-order)
//   blocks 0..255 zero d_out (1 MB).
__global__ __launch_bounds__(256) void prep_frags(const float* __restrict__ ls,
                                                  const float* __restrict__ y,
                                                  const float* __restrict__ b,
                                                  bf8* __restrict__ ytbl,
                                                  bf8* __restrict__ btbl,
                                                  float4* __restrict__ outz) {
    const int w = blockIdx.x * 4 + (threadIdx.x >> 6);    // global wave id
    const int lane = threadIdx.x & 63;
    const int n = lane & 15, quad = lane >> 4;

    if (blockIdx.x < 256)
        outz[blockIdx.x * 256 + threadIdx.x] = make_float4(0.f, 0.f, 0.f, 0.f);

    float lsv[DD];
#pragma unroll
    for (int d = 0; d < DD; ++d) lsv[d] = ls[d];

    if (w < 1024) {                   // ---- ytbl tile16 = w ----
        const int tile = w;
        const float4* yr4 = (const float4*)(y + (size_t)(tile * 16 + n) * DD);
        float4 ya = yr4[0], yb = yr4[1];
        float yv[DD] = {ya.x, ya.y, ya.z, ya.w, yb.x, yb.y, yb.z, yb.w};

        float syv = 0.f;
        unsigned short wh[DD], wl[DD];
#pragma unroll
        for (int d = 0; d < DD; ++d) {
            syv = fmaf(lsv[d] * yv[d], yv[d], syv);
            float wv = -2.f * C3SQ * yv[d];     // scale in fp32, THEN split
            wh[d] = f2bf(wv);
            wl[d] = f2bf(wv - bf2f(wh[d]));
        }

        bf8 fr;
        if (quad < 3) {
#pragma unroll
            for (int d = 0; d < DD; ++d)
                fr[d] = (short)((quad == 2) ? wl[d] : wh[d]);
        } else {
            float csy = C3SQ * syv;
            unsigned short sh = f2bf(csy);
            unsigned short sl = f2bf(csy - bf2f(sh));
            fr[0] = (short)sh;      // k=24: 1 * csy_hi
            fr[1] = (short)sl;      // k=25: 1 * csy_lo
            fr[2] = BF16_ONE;       // k=26: csx_hi * 1
            fr[3] = BF16_ONE;       // k=27: csx_lo * 1
            fr[4] = 0; fr[5] = 0; fr[6] = 0; fr[7] = 0;
        }
        ytbl[tile * 64 + lane] = fr;
    } else {                          // ---- btbl tile32 = w - 1024 ----
        const int tile = w - 1024;    // 0..511
        bf8 bfr;
#pragma unroll
        for (int s = 0; s < 8; ++s) {
            int k = quad * 8 + s;
            int jl = (k >> 1) + ((k & 1) << 4);   // interleaved klds col -> j
            float bv = b[(size_t)(tile * 32 + jl) * DV + n];
            bfr[s] = (short)f2bf(bv);
        }
        btbl[tile * 64 + lane] = bfr;
    }
}

// R15 structure (proven PASS, main 89us; R16's unroll-2 reverted — neutral)
// with ONE change: v_exp_f32 -> fast_exp2 (floor/sub/3fma/cvt/ldexp, all
// full-rate VALU). Halves the trans-pipe load (only sqrt remains), which
// the cycle model says was 61% of the wall at 16 cyc/op.
__global__ __launch_bounds__(256, 8) void matern_mfma(const float* __restrict__ ls,
                                                      const float* __restrict__ x,
                                                      const bf8* __restrict__ ytbl,
                                                      const bf8* __restrict__ btbl,
                                                      float* __restrict__ out) {
    const int t = threadIdx.x;
    const int lane = t & 63, wave = t >> 6;
    const int n = lane & 15, quad = lane >> 4;
    const int waverow = blockIdx.x * ROWS_BLK + wave * ROWS_WAVE;

    __shared__ __attribute__((aligned(16))) unsigned short klds[WAVES][MT][16][40];

    float lsv[DD];
#pragma unroll
    for (int d = 0; d < DD; ++d) lsv[d] = ls[d];

    // A-frags: quad 0/2 -> xls_hi, quad 1 -> xls_lo, quad 3 -> {1,1,csx_hi,csx_lo}
    bf8 afrag[MT];
#pragma unroll
    for (int mt = 0; mt < MT; ++mt) {
        const float* xr = x + (size_t)(waverow + mt * 16 + n) * DD;
        float sx = 0.f;
        unsigned short xh[DD], xl[DD];
#pragma unroll
        for (int d = 0; d < DD; ++d) {
            float xv = xr[d];
            float xlsv = lsv[d] * xv;
            sx = fmaf(xlsv, xv, sx);
            xh[d] = f2bf(xlsv);
            xl[d] = f2bf(xlsv - bf2f(xh[d]));
        }
        bf8 fr;
        if (quad == 3) {
            float csx = C3SQ * sx;               // scale in fp32, THEN split
            unsigned short sh = f2bf(csx);
            unsigned short sl = f2bf(csx - bf2f(sh));
            fr[0] = BF16_ONE;   // k=24: 1 * csy_hi
            fr[1] = BF16_ONE;   // k=25: 1 * csy_lo
            fr[2] = (short)sh;  // k=26: csx_hi * 1
            fr[3] = (short)sl;  // k=27: csx_lo * 1
            fr[4] = 0; fr[5] = 0; fr[6] = 0; fr[7] = 0;
        } else {
#pragma unroll
            for (int d = 0; d < DD; ++d)
                fr[d] = (short)((quad == 1) ? xl[d] : xh[d]);
        }
        afrag[mt] = fr;
    }

    f32x4 acc[MT];
#pragma unroll
    for (int mt = 0; mt < MT; ++mt) acc[mt] = (f32x4){0.f, 0.f, 0.f, 0.f};

    const int tile16base = blockIdx.y * (JCHUNK / 16);
    const int tile32base = blockIdx.y * (JCHUNK / 32);

    // Live tables for iter 0
    bf8 yA = ytbl[(size_t)tile16base * 64 + lane];
    bf8 yB = ytbl[(size_t)(tile16base + 1) * 64 + lane];
    bf8 bb = btbl[(size_t)tile32base * 64 + lane];

#pragma unroll 1
    for (int it = 0; it < J32; ++it) {
#pragma unroll
        for (int mt = 0; mt < MT; ++mt) {
            f32x4 z = (f32x4){0.f, 0.f, 0.f, 0.f};
            f32x4 s0 = __builtin_amdgcn_mfma_f32_16x16x32_bf16(afrag[mt], yA, z, 0, 0, 0);
            f32x4 s1 = __builtin_amdgcn_mfma_f32_16x16x32_bf16(afrag[mt], yB, z, 0, 0, 0);
#pragma unroll
            for (int s = 0; s < 4; ++s) {
                // s0/s1 ARE c3sq*d2; |.| eats rounding-noise negatives (free mod)
                float a0 = __builtin_fabsf(s0[s]);
                float a1 = __builtin_fabsf(s1[s]);
                float t0 = __builtin_amdgcn_sqrtf(a0);          // = |c3|*r
                float t1 = __builtin_amdgcn_sqrtf(a1);
                float e0 = fast_exp2(-t0);                      // VALU-pipe exp2
                float e1 = fast_exp2(-t1);
                float k0 = fmaf(C2S, a0, fmaf(LN2, t0, 1.f)) * e0;
                float k1 = fmaf(C2S, a1, fmaf(LN2, t1, 1.f)) * e1;
                s2v w;
#if __has_builtin(__builtin_amdgcn_cvt_pk_bf16_f32)
                typedef __bf16 bf2v __attribute__((ext_vector_type(2)));
                bf2v pk = __builtin_amdgcn_cvt_pk_bf16_f32(k0, k1);
                union { bf2v v; s2v s; } cv; cv.v = pk;
                w = cv.s;
#else
                w[0] = (short)((__float_as_uint(k0) + 0x8000u) >> 16);
                w[1] = (short)((__float_as_uint(k1) + 0x8000u) >> 16);
#endif
                // one b32 store: cols 2n (tile0) / 2n+1 (tile1), interleaved
                *(s2v*)&klds[wave][mt][quad * 4 + s][2 * n] = w;
            }
        }

        // Prefetch next iter into SEPARATE regs (bb stays live for phase B;
        // rotation strictly after phase B below).
        bf8 yAn, yBn, bbn;
        if (it + 1 < J32) {
            const int tl = tile16base + (it + 1) * 2;
            yAn = ytbl[(size_t)tl * 64 + lane];
            yBn = ytbl[(size_t)(tl + 1) * 64 + lane];
            bbn = btbl[(size_t)(tile32base + it + 1) * 64 + lane];
        }

        // Phase B: C/D->A via wave-private LDS (interleaved cols = btbl K-order)
#pragma unroll
        for (int mt = 0; mt < MT; ++mt) {
            const bf8* kp = (const bf8*)&klds[wave][mt][n][quad * 8];
            acc[mt] = __builtin_amdgcn_mfma_f32_16x16x32_bf16(*kp, bb, acc[mt], 0, 0, 0);
        }

        if (it + 1 < J32) { yA = yAn; yB = yBn; bb = bbn; }
    }

    // Epilogue: D layout row=quad*4+s, col=n; JSPLIT partial sums via atomics
#pragma unroll
    for (int mt = 0; mt < MT; ++mt)
#pragma unroll
        for (int s = 0; s < 4; ++s) {
            const int row = waverow + mt * 16 + quad * 4 + s;
            atomicAdd(out + (size_t)row * DV + n, acc[mt][s]);
        }
}

extern "C" void kernel_launch(void* const* d_in, const int* in_sizes, int n_in,
                              void* d_out, int out_size, void* d_ws, size_t ws_size,
                              hipStream_t stream) {
    const float* ls = (const float*)d_in[0];
    const float* x  = (const float*)d_in[1];
    const float* y  = (const float*)d_in[2];
    const float* b  = (const float*)d_in[3];
    float* out = (float*)d_out;

    char* ws = (char*)d_ws;
    bf8* ytbl = (bf8*)ws;                        // 1024*64*16B = 1 MB
    bf8* btbl = (bf8*)(ws + (1 << 20));          // 512*64*16B  = 512 KB

    prep_frags<<<384, 256, 0, stream>>>(ls, y, b, ytbl, btbl, (float4*)out);
    matern_mfma<<<dim3(NN / ROWS_BLK, JSPLIT), 256, 0, stream>>>(ls, x, ytbl, btbl, out);
}

// Round 18
// 138.301 us; speedup vs baseline: 1.1562x; 1.1562x over previous
//
#include <hip/hip_runtime.h>
#include <stdint.h>

#define NN 16384
#define MM 16384
#define DD 8
#define DV 16
#define WAVES 4
#define MT 2                        // 16-row m-tiles per wave
#define ROWS_WAVE (MT * 16)         // 32
#define ROWS_BLK (WAVES * ROWS_WAVE)// 128
#define JSPLIT 32
#define JCHUNK (MM / JSPLIT)        // 512
#define J32 (JCHUNK / 32)           // 16 iterations per block

typedef short bf8 __attribute__((ext_vector_type(8)));   // 8 bf16 (4 VGPR)
typedef short s2v __attribute__((ext_vector_type(2)));   // 2 bf16, one b32 store
typedef float f32x4 __attribute__((ext_vector_type(4))); // MFMA C/D

#define C3SQ 10.406844905028037f     /* 5*log2(e)^2 : folded into tables */
#define C2S  (1.2909944487358056f / 10.406844905028037f)  /* c2/c3sq */
#define LN2  0.6931471805599453f

#define TBLN 1024
#define ZMAX 416.0f                  /* z = c3sq*d2 table range (d2 <= 40) */
#define HZ   (ZMAX / TBLN)
#define INVHZ (TBLN / ZMAX)

__device__ __forceinline__ unsigned short f2bf(float f) {
    union { float f; uint32_t u; } c; c.f = f;
    uint32_t u = c.u + 0x7FFF + ((c.u >> 16) & 1);       // RNE
    return (unsigned short)(u >> 16);
}
__device__ __forceinline__ float bf2f(unsigned short h) {
    union { float f; uint32_t u; } c; c.u = ((uint32_t)h) << 16;
    return c.f;
}
__device__ __forceinline__ float kofz(float z) {         // exact k(z), prep only
    float tq = __builtin_amdgcn_sqrtf(z);
    float e = __builtin_amdgcn_exp2f(-tq);
    return fmaf(C2S, z, fmaf(LN2, tq, 1.f)) * e;
}

#define BF16_ONE ((short)0x3F80)

// Prep (R15 shape + table): one WAVE per table tile -> 1536 waves.
//   waves    0..1023: ytbl[tile16]  (scaled d2 fold)
//   waves 1024..1535: btbl[tile32]  (PERMUTED K-order)
//   block 384: k(z) lookup table, 1024 x float2{base, delta}
//   blocks 0..255 zero d_out (1 MB).
__global__ __launch_bounds__(256) void prep_frags(const float* __restrict__ ls,
                                                  const float* __restrict__ y,
                                                  const float* __restrict__ b,
                                                  bf8* __restrict__ ytbl,
                                                  bf8* __restrict__ btbl,
                                                  float2* __restrict__ ktbl,
                                                  float4* __restrict__ outz) {
    const int lane = threadIdx.x & 63;
    const int n = lane & 15, quad = lane >> 4;

    if (blockIdx.x == 384) {          // ---- k(z) table ----
        for (int i = threadIdx.x; i < TBLN; i += 256) {
            float z0 = i * HZ;
            float k0 = kofz(z0);
            float k1 = kofz(z0 + HZ);
            ktbl[i] = make_float2(k0, k1 - k0);
        }
        return;
    }

    const int w = blockIdx.x * 4 + (threadIdx.x >> 6);    // global wave id

    if (blockIdx.x < 256)
        outz[blockIdx.x * 256 + threadIdx.x] = make_float4(0.f, 0.f, 0.f, 0.f);

    float lsv[DD];
#pragma unroll
    for (int d = 0; d < DD; ++d) lsv[d] = ls[d];

    if (w < 1024) {                   // ---- ytbl tile16 = w ----
        const int tile = w;
        const float4* yr4 = (const float4*)(y + (size_t)(tile * 16 + n) * DD);
        float4 ya = yr4[0], yb = yr4[1];
        float yv[DD] = {ya.x, ya.y, ya.z, ya.w, yb.x, yb.y, yb.z, yb.w};

        float syv = 0.f;
        unsigned short wh[DD], wl[DD];
#pragma unroll
        for (int d = 0; d < DD; ++d) {
            syv = fmaf(lsv[d] * yv[d], yv[d], syv);
            float wv = -2.f * C3SQ * yv[d];     // scale in fp32, THEN split
            wh[d] = f2bf(wv);
            wl[d] = f2bf(wv - bf2f(wh[d]));
        }

        bf8 fr;
        if (quad < 3) {
#pragma unroll
            for (int d = 0; d < DD; ++d)
                fr[d] = (short)((quad == 2) ? wl[d] : wh[d]);
        } else {
            float csy = C3SQ * syv;
            unsigned short sh = f2bf(csy);
            unsigned short sl = f2bf(csy - bf2f(sh));
            fr[0] = (short)sh;      // k=24: 1 * csy_hi
            fr[1] = (short)sl;      // k=25: 1 * csy_lo
            fr[2] = BF16_ONE;       // k=26: csx_hi * 1
            fr[3] = BF16_ONE;       // k=27: csx_lo * 1
            fr[4] = 0; fr[5] = 0; fr[6] = 0; fr[7] = 0;
        }
        ytbl[tile * 64 + lane] = fr;
    } else {                          // ---- btbl tile32 = w - 1024 ----
        const int tile = w - 1024;    // 0..511
        bf8 bfr;
#pragma unroll
        for (int s = 0; s < 8; ++s) {
            int k = quad * 8 + s;
            int jl = (k >> 1) + ((k & 1) << 4);   // interleaved klds col -> j
            float bv = b[(size_t)(tile * 32 + jl) * DV + n];
            bfr[s] = (short)f2bf(bv);
        }
        btbl[tile * 64 + lane] = bfr;
    }
}

// R15 structure (proven PASS, main 89us) with ONE change: the Matern
// transform is a 1024-entry LDS linear-interp lookup in z = c3sq*d2 (the
// MFMA's direct output) — removes BOTH transcendentals (2x16 cyc issue
// each, 61% of R15's VALU busy per the R15/R17 cycle fit). Interp error
// <=1e-3 (worst in the s^(3/2) bins near 0) -> out contribution ~0.1 of
// the 1.63 budget. R17's trans->VALU-chain swap regressed; lesson: remove
// trans ops, don't convert them.
__global__ __launch_bounds__(256, 8) void matern_mfma(const float* __restrict__ ls,
                                                      const float* __restrict__ x,
                                                      const bf8* __restrict__ ytbl,
                                                      const bf8* __restrict__ btbl,
                                                      const float2* __restrict__ ktbl,
                                                      float* __restrict__ out) {
    const int t = threadIdx.x;
    const int lane = t & 63, wave = t >> 6;
    const int n = lane & 15, quad = lane >> 4;
    const int waverow = blockIdx.x * ROWS_BLK + wave * ROWS_WAVE;

    __shared__ __attribute__((aligned(16))) unsigned short klds[WAVES][MT][16][40];
    __shared__ __attribute__((aligned(16))) float2 ktbl_s[TBLN];   // 8 KB

    // One-time: stage k-table into LDS (per block), then barrier.
    for (int i = t; i < TBLN; i += 256) ktbl_s[i] = ktbl[i];

    float lsv[DD];
#pragma unroll
    for (int d = 0; d < DD; ++d) lsv[d] = ls[d];

    // A-frags: quad 0/2 -> xls_hi, quad 1 -> xls_lo, quad 3 -> {1,1,csx_hi,csx_lo}
    bf8 afrag[MT];
#pragma unroll
    for (int mt = 0; mt < MT; ++mt) {
        const float* xr = x + (size_t)(waverow + mt * 16 + n) * DD;
        float sx = 0.f;
        unsigned short xh[DD], xl[DD];
#pragma unroll
        for (int d = 0; d < DD; ++d) {
            float xv = xr[d];
            float xlsv = lsv[d] * xv;
            sx = fmaf(xlsv, xv, sx);
            xh[d] = f2bf(xlsv);
            xl[d] = f2bf(xlsv - bf2f(xh[d]));
        }
        bf8 fr;
        if (quad == 3) {
            float csx = C3SQ * sx;               // scale in fp32, THEN split
            unsigned short sh = f2bf(csx);
            unsigned short sl = f2bf(csx - bf2f(sh));
            fr[0] = BF16_ONE;   // k=24: 1 * csy_hi
            fr[1] = BF16_ONE;   // k=25: 1 * csy_lo
            fr[2] = (short)sh;  // k=26: csx_hi * 1
            fr[3] = (short)sl;  // k=27: csx_lo * 1
            fr[4] = 0; fr[5] = 0; fr[6] = 0; fr[7] = 0;
        } else {
#pragma unroll
            for (int d = 0; d < DD; ++d)
                fr[d] = (short)((quad == 1) ? xl[d] : xh[d]);
        }
        afrag[mt] = fr;
    }

    f32x4 acc[MT];
#pragma unroll
    for (int mt = 0; mt < MT; ++mt) acc[mt] = (f32x4){0.f, 0.f, 0.f, 0.f};

    const int tile16base = blockIdx.y * (JCHUNK / 16);
    const int tile32base = blockIdx.y * (JCHUNK / 32);

    // Live tables for iter 0
    bf8 yA = ytbl[(size_t)tile16base * 64 + lane];
    bf8 yB = ytbl[(size_t)(tile16base + 1) * 64 + lane];
    bf8 bb = btbl[(size_t)tile32base * 64 + lane];

    __syncthreads();                 // k-table visible to all waves

#pragma unroll 1
    for (int it = 0; it < J32; ++it) {
#pragma unroll
        for (int mt = 0; mt < MT; ++mt) {
            f32x4 z = (f32x4){0.f, 0.f, 0.f, 0.f};
            f32x4 s0 = __builtin_amdgcn_mfma_f32_16x16x32_bf16(afrag[mt], yA, z, 0, 0, 0);
            f32x4 s1 = __builtin_amdgcn_mfma_f32_16x16x32_bf16(afrag[mt], yB, z, 0, 0, 0);
#pragma unroll
            for (int s = 0; s < 4; ++s) {
                // s0/s1 ARE c3sq*d2; |.| (free mod) eats rounding negatives.
                float i0f = fminf(__builtin_fabsf(s0[s]) * INVHZ, 1023.0f);
                float i1f = fminf(__builtin_fabsf(s1[s]) * INVHZ, 1023.0f);
                int i0 = (int)i0f;
                int i1 = (int)i1f;
                float fr0 = i0f - (float)i0;
                float fr1 = i1f - (float)i1;
                float2 e0 = ktbl_s[i0];
                float2 e1 = ktbl_s[i1];
                float k0 = fmaf(e0.y, fr0, e0.x);
                float k1 = fmaf(e1.y, fr1, e1.x);
                s2v w;
#if __has_builtin(__builtin_amdgcn_cvt_pk_bf16_f32)
                typedef __bf16 bf2v __attribute__((ext_vector_type(2)));
                bf2v pk = __builtin_amdgcn_cvt_pk_bf16_f32(k0, k1);
                union { bf2v v; s2v s; } cv; cv.v = pk;
                w = cv.s;
#else
                w[0] = (short)((__float_as_uint(k0) + 0x8000u) >> 16);
                w[1] = (short)((__float_as_uint(k1) + 0x8000u) >> 16);
#endif
                // one b32 store: cols 2n (tile0) / 2n+1 (tile1), interleaved
                *(s2v*)&klds[wave][mt][quad * 4 + s][2 * n] = w;
            }
        }

        // Prefetch next iter into SEPARATE regs (bb stays live for phase B;
        // rotation strictly after phase B below).
        bf8 yAn, yBn, bbn;
        if (it + 1 < J32) {
            const int tl = tile16base + (it + 1) * 2;
            yAn = ytbl[(size_t)tl * 64 + lane];
            yBn = ytbl[(size_t)(tl + 1) * 64 + lane];
            bbn = btbl[(size_t)(tile32base + it + 1) * 64 + lane];
        }

        // Phase B: C/D->A via wave-private LDS (interleaved cols = btbl K-order)
#pragma unroll
        for (int mt = 0; mt < MT; ++mt) {
            const bf8* kp = (const bf8*)&klds[wave][mt][n][quad * 8];
            acc[mt] = __builtin_amdgcn_mfma_f32_16x16x32_bf16(*kp, bb, acc[mt], 0, 0, 0);
        }

        if (it + 1 < J32) { yA = yAn; yB = yBn; bb = bbn; }
    }

    // Epilogue: D layout row=quad*4+s, col=n; JSPLIT partial sums via atomics
#pragma unroll
    for (int mt = 0; mt < MT; ++mt)
#pragma unroll
        for (int s = 0; s < 4; ++s) {
            const int row = waverow + mt * 16 + quad * 4 + s;
            atomicAdd(out + (size_t)row * DV + n, acc[mt][s]);
        }
}

extern "C" void kernel_launch(void* const* d_in, const int* in_sizes, int n_in,
                              void* d_out, int out_size, void* d_ws, size_t ws_size,
                              hipStream_t stream) {
    const float* ls = (const float*)d_in[0];
    const float* x  = (const float*)d_in[1];
    const float* y  = (const float*)d_in[2];
    const float* b  = (const float*)d_in[3];
    float* out = (float*)d_out;

    char* ws = (char*)d_ws;
    bf8*    ytbl = (bf8*)ws;                              // 1024*64*16B = 1 MB
    bf8*    btbl = (bf8*)(ws + (1 << 20));                // 512*64*16B = 512 KB
    float2* ktbl = (float2*)(ws + (1 << 20) + (512 << 10)); // 1024*8B = 8 KB

    prep_frags<<<385, 256, 0, stream>>>(ls, y, b, ytbl, btbl, ktbl, (float4*)out);
    matern_mfma<<<dim3(NN / ROWS_BLK, JSPLIT), 256, 0, stream>>>(ls, x, ytbl, btbl, ktbl, out);
}